// Round 8
// baseline (873.527 us; speedup 1.0000x reference)
//
#include <hip/hip_runtime.h>

// VariationalLSTM: B=65536, T=24, H=64. 4096 WGs x 256 thr (4 waves); each WG owns
// ONE 16-row batch tile for all 24 steps. Wave w owns gate units u = 16w + (lane&15).
// LDS layout (R1-proven): bf16 tiles [16 rows m][64 units u], XOR swizzle
// byte ^= (m&7)<<4; A-frags via ds_read_b128, k-map f(kk,hi,e)=32kk+8hi+e shared
// by A and B. Double-buffered tiles -> ONE barrier per timestep. cvt_pk stores.
//
// Occupancy model (R1-R5 counters): builtin MFMA + __launch_bounds__(256,N) =>
// per-wave alloc = 512/N total, accum_offset = half (arch cap 256/N), runtime
// waves/SIMD = N. So N=3 gives 3 waves/SIMD IF arch<=85 and agpr<=85:
//  - 21 of 24 weight frags pinned to AGPR via empty asm "+a" (84 AGPRs);
//    MFMA builtins read A/B from AGPR directly (gfx950 unified file).
//  - dropout masks packed as bf16 pairs (values {0,1.25} are bf16-exact): -8 arch.
// asm MFMA abandoned: opaque to the hazard recognizer -> silent corruption (R6/R7).
//
// Activation prescale folded into weights: i,f,o rows of W/b scaled by -log2e
// (sigmoid = rcp(1+exp2(y))); g rows scaled by +2*log2e (tanh = 1-2*rcp(1+exp2(y))).

typedef short short8v __attribute__((ext_vector_type(8)));
typedef float f32x4 __attribute__((ext_vector_type(4)));

#define LOG2E 1.44269504088896340736f

__device__ inline float gsig(float y){      // sigmoid of prescaled gate (y = -log2e*x)
  return __builtin_amdgcn_rcpf(1.0f + __builtin_amdgcn_exp2f(y));
}
__device__ inline float gtanh(float y){     // tanh of prescaled gate (y = 2*log2e*x)
  float s = __builtin_amdgcn_rcpf(1.0f + __builtin_amdgcn_exp2f(y));
  return fmaf(-2.0f, s, 1.0f);
}
__device__ inline float ftanh(float x){     // tanh of fp32 value (cell state)
  float e = __builtin_amdgcn_exp2f((2.0f * LOG2E) * x);
  return fmaf(-2.0f, __builtin_amdgcn_rcpf(1.0f + e), 1.0f);
}
__device__ inline unsigned short bf16c(float f){  // RNE f32->bf16 (init only)
  unsigned uu = __builtin_bit_cast(unsigned, f);
  uu = (uu + 0x7fffu + ((uu >> 16) & 1u)) >> 16;
  return (unsigned short)uu;
}
// unpack half h of a bf16 pair to f32 (exact)
__device__ inline float unpk(unsigned p, int h){
  unsigned b = h ? (p & 0xffff0000u) : (p << 16);
  return __builtin_bit_cast(float, b);
}

// 4 rows (same unit column u) -> 2x v_cvt_pk_bf16_f32 (D.lo=S0 per T12) + 4x b16.
#define PK_STORE4(T, I, f0, f1, f2, f3) do{                       \
    unsigned _w01, _w23;                                          \
    asm("v_cvt_pk_bf16_f32 %0, %1, %2" : "=v"(_w01) : "v"(f0), "v"(f1)); \
    asm("v_cvt_pk_bf16_f32 %0, %1, %2" : "=v"(_w23) : "v"(f2), "v"(f3)); \
    (T)[(I)[0]] = (unsigned short)_w01;                           \
    (T)[(I)[1]] = (unsigned short)(_w01 >> 16);                   \
    (T)[(I)[2]] = (unsigned short)_w23;                           \
    (T)[(I)[3]] = (unsigned short)(_w23 >> 16);                   \
  }while(0)

__global__ __launch_bounds__(256, 3) void vlstm_kernel(
    const float* __restrict__ x,
    const float* __restrict__ Wih1, const float* __restrict__ Whh1,
    const float* __restrict__ bih1, const float* __restrict__ bhh1,
    const float* __restrict__ Wih2, const float* __restrict__ Whh2,
    const float* __restrict__ bih2, const float* __restrict__ bhh2,
    const float* __restrict__ Wout, const float* __restrict__ bout,
    const float* __restrict__ h10, const float* __restrict__ c10,
    const float* __restrict__ h20, const float* __restrict__ c20,
    const float* __restrict__ mt1v, const float* __restrict__ mt2v,
    const float* __restrict__ ml1v, const float* __restrict__ ml2v,
    float* __restrict__ out)
{
  __shared__ unsigned short sh1L[2][1024];  // h1*m_layer1           (layer2 input)
  __shared__ unsigned short sh1T[2][1024];  // h1*m_layer1*m_time1   (next-step L1 h)
  __shared__ unsigned short sh2T[2][1024];  // h2*m_layer2*m_time2   (next-step L2 h)
  __shared__ float h2f[1024];               // final h2 (fp32)
  __shared__ float xlds[384];               // x transposed [24][16]

  const int tid = threadIdx.x;
  const int w  = tid >> 6;
  const int l  = tid & 63;
  const int hi = l >> 4;
  const int lo = l & 15;
  const int u  = 16 * w + lo;               // gate unit owned (D col = lane&15)

  // ---- one-time: prescaled biases/x-coeffs/weight B-frags (k-map 32kk+8hi+e) ----
  // gate j: 0=i, 1=f, 2=g, 3=o.  scale = -LOG2E for i,f,o; +2*LOG2E for g.
  float b1v[4], b2v[4], wiv[4];
  short8v fr1[4][2], frI[4][2], frH[4][2];
#pragma unroll
  for (int j = 0; j < 4; ++j){
    const float sc = (j == 2) ? (2.0f * LOG2E) : (-LOG2E);
    int n = u + 64 * j;
    b1v[j] = sc * (bih1[n] + bhh1[n]);
    b2v[j] = sc * (bih2[n] + bhh2[n]);
    wiv[j] = sc * Wih1[n];
#pragma unroll
    for (int kk = 0; kk < 2; ++kk){
      int off = n * 64 + 32 * kk + 8 * hi;
      short8v s;
#pragma unroll
      for (int e = 0; e < 8; ++e) s[e] = (short)bf16c(sc * Whh1[off + e]);
      fr1[j][kk] = s;
#pragma unroll
      for (int e = 0; e < 8; ++e) s[e] = (short)bf16c(sc * Wih2[off + e]);
      frI[j][kk] = s;
#pragma unroll
      for (int e = 0; e < 8; ++e) s[e] = (short)bf16c(sc * Whh2[off + e]);
      frH[j][kk] = s;
    }
  }

  // Pin 21/24 weight frags into AGPRs (84 of the 85 AGPR half at N=3).
  // Builtin MFMA reads A/B from AGPR directly; hazards stay compiler-handled.
  asm volatile("" :
    "+a"(fr1[0][0]), "+a"(fr1[0][1]), "+a"(fr1[1][0]), "+a"(fr1[1][1]),
    "+a"(fr1[2][0]), "+a"(fr1[2][1]), "+a"(fr1[3][0]), "+a"(fr1[3][1]),
    "+a"(frI[0][0]), "+a"(frI[0][1]), "+a"(frI[1][0]), "+a"(frI[1][1]),
    "+a"(frI[2][0]), "+a"(frI[2][1]), "+a"(frI[3][0]), "+a"(frI[3][1]),
    "+a"(frH[0][0]), "+a"(frH[0][1]), "+a"(frH[1][0]), "+a"(frH[1][1]),
    "+a"(frH[2][0]));

  // ---- swizzled LDS offsets (ushort indices), byte ^= (m&7)<<4 ----
  int wIdx[4];                 // writes: rows m = 4hi+r, col u
#pragma unroll
  for (int r = 0; r < 4; ++r){
    int m = 4 * hi + r;
    wIdx[r] = ((m * 128 + u * 2) ^ ((m & 7) << 4)) >> 1;
  }
  int rIdx[2];                 // A-frag b128 reads: m = lo, k = 32kk + 8hi + e
#pragma unroll
  for (int kk = 0; kk < 2; ++kk){
    rIdx[kk] = ((lo * 128 + kk * 64 + hi * 16) ^ ((lo & 7) << 4)) >> 1;
  }

  const int row0 = blockIdx.x * 16;

  for (int idx = tid; idx < 384; idx += 256){
    int r = idx / 24, tt = idx - r * 24;
    xlds[tt * 16 + r] = x[(row0 + r) * 24 + tt];
  }
  // states + masks; masks packed to bf16 pairs (values {0,1.25} exact in bf16)
  float c1r[4], c2r[4];
  unsigned ml1p[2], mt1p[2], ml2p[2], mt2p[2];
  {
    float mlt1[4], mtt1[4], mlt2[4], mtt2[4], h1i[4], h2i[4];
#pragma unroll
    for (int r = 0; r < 4; ++r){
      int gofs = (row0 + 4 * hi + r) * 64 + u;
      c1r[r]  = c10[gofs];  c2r[r]  = c20[gofs];
      mlt1[r] = ml1v[gofs]; mlt2[r] = ml2v[gofs];
      mtt1[r] = mt1v[gofs]; mtt2[r] = mt2v[gofs];
      h1i[r] = h10[gofs] * mtt1[r];
      h2i[r] = h20[gofs] * mtt2[r];
    }
#pragma unroll
    for (int pr = 0; pr < 2; ++pr){
      ml1p[pr] = (unsigned)bf16c(mlt1[2*pr]) | ((unsigned)bf16c(mlt1[2*pr+1]) << 16);
      mt1p[pr] = (unsigned)bf16c(mtt1[2*pr]) | ((unsigned)bf16c(mtt1[2*pr+1]) << 16);
      ml2p[pr] = (unsigned)bf16c(mlt2[2*pr]) | ((unsigned)bf16c(mlt2[2*pr+1]) << 16);
      mt2p[pr] = (unsigned)bf16c(mtt2[2*pr]) | ((unsigned)bf16c(mtt2[2*pr+1]) << 16);
    }
    PK_STORE4(sh1T[0], wIdx, h1i[0], h1i[1], h1i[2], h1i[3]);
    PK_STORE4(sh2T[0], wIdx, h2i[0], h2i[1], h2i[2], h2i[3]);
  }
  __syncthreads();

  short8v a1[2], at2[2];
  a1[0] = *(const short8v*)&sh1T[0][rIdx[0]];
  a1[1] = *(const short8v*)&sh1T[0][rIdx[1]];

  int P = 0;
#pragma unroll 1
  for (int t = 0; t < 24; ++t){
    const int Q = P ^ 1;
    f32x4 xv = *(const f32x4*)&xlds[t * 16 + 4 * hi];

    // ---- layer 1 (reads a1 = h1T[P], preloaded) ----
    f32x4 gt[4];
#pragma unroll
    for (int j = 0; j < 4; ++j){
      f32x4 acc;
#pragma unroll
      for (int r = 0; r < 4; ++r) acc[r] = fmaf(xv[r], wiv[j], b1v[j]);
      acc = __builtin_amdgcn_mfma_f32_16x16x32_bf16(a1[0], fr1[j][0], acc, 0, 0, 0);
      acc = __builtin_amdgcn_mfma_f32_16x16x32_bf16(a1[1], fr1[j][1], acc, 0, 0, 0);
      gt[j] = acc;
    }
    float h1l[4], h1t[4];
#pragma unroll
    for (int r = 0; r < 4; ++r){
      float ti = gsig(gt[0][r]);
      float tf = gsig(gt[1][r]);
      float tg = gtanh(gt[2][r]);
      float to = gsig(gt[3][r]);
      float cn = fmaf(tf, c1r[r], ti * tg);
      c1r[r] = cn;
      h1l[r] = to * ftanh(cn) * unpk(ml1p[r >> 1], r & 1);
      h1t[r] = h1l[r] * unpk(mt1p[r >> 1], r & 1);
    }
    PK_STORE4(sh1L[Q], wIdx, h1l[0], h1l[1], h1l[2], h1l[3]);
    PK_STORE4(sh1T[Q], wIdx, h1t[0], h1t[1], h1t[2], h1t[3]);

    __syncthreads();   // the ONLY barrier per step

    short8v a2[2];
    a2[0]  = *(const short8v*)&sh1L[Q][rIdx[0]];
    a2[1]  = *(const short8v*)&sh1L[Q][rIdx[1]];
    a1[0]  = *(const short8v*)&sh1T[Q][rIdx[0]];   // next step's layer-1 input
    a1[1]  = *(const short8v*)&sh1T[Q][rIdx[1]];
    at2[0] = *(const short8v*)&sh2T[P][rIdx[0]];   // h2T written at t-1 (or init)
    at2[1] = *(const short8v*)&sh2T[P][rIdx[1]];

    // ---- layer 2 ----
#pragma unroll
    for (int j = 0; j < 4; ++j){
      f32x4 acc;
#pragma unroll
      for (int r = 0; r < 4; ++r) acc[r] = b2v[j];
      acc = __builtin_amdgcn_mfma_f32_16x16x32_bf16(a2[0],  frI[j][0], acc, 0, 0, 0);
      acc = __builtin_amdgcn_mfma_f32_16x16x32_bf16(a2[1],  frI[j][1], acc, 0, 0, 0);
      acc = __builtin_amdgcn_mfma_f32_16x16x32_bf16(at2[0], frH[j][0], acc, 0, 0, 0);
      acc = __builtin_amdgcn_mfma_f32_16x16x32_bf16(at2[1], frH[j][1], acc, 0, 0, 0);
      gt[j] = acc;
    }
    float h2t[4];
#pragma unroll
    for (int r = 0; r < 4; ++r){
      float ti = gsig(gt[0][r]);
      float tf = gsig(gt[1][r]);
      float tg = gtanh(gt[2][r]);
      float to = gsig(gt[3][r]);
      float cn = fmaf(tf, c2r[r], ti * tg);
      c2r[r] = cn;
      float h2l = to * ftanh(cn) * unpk(ml2p[r >> 1], r & 1);
      h2t[r] = h2l * unpk(mt2p[r >> 1], r & 1);
      if (t == 23) h2f[(4 * hi + r) * 64 + u] = h2l;
    }
    PK_STORE4(sh2T[Q], wIdx, h2t[0], h2t[1], h2t[2], h2t[3]);  // post-barrier write

    P = Q;
  }
  __syncthreads();   // h2f visible to reducer

  // ---- output: out[row][o] = sum_u h2f[row][u]*Wout[o][u] + bout[o] ----
  if (tid < 32){
    int r = tid & 15, o = tid >> 4;
    float acc = bout[o];
#pragma unroll 8
    for (int uu = 0; uu < 64; ++uu)
      acc = fmaf(h2f[r * 64 + uu], Wout[o * 64 + uu], acc);
    out[(row0 + r) * 2 + o] = acc;
  }
}

extern "C" void kernel_launch(void* const* d_in, const int* in_sizes, int n_in,
                              void* d_out, int out_size, void* d_ws, size_t ws_size,
                              hipStream_t stream)
{
  vlstm_kernel<<<dim3(4096), dim3(256), 0, stream>>>(
      (const float*)d_in[0],  (const float*)d_in[1],  (const float*)d_in[2],
      (const float*)d_in[3],  (const float*)d_in[4],  (const float*)d_in[5],
      (const float*)d_in[6],  (const float*)d_in[7],  (const float*)d_in[8],
      (const float*)d_in[9],  (const float*)d_in[10], (const float*)d_in[11],
      (const float*)d_in[12], (const float*)d_in[13], (const float*)d_in[14],
      (const float*)d_in[15], (const float*)d_in[16], (const float*)d_in[17],
      (const float*)d_in[18], (float*)d_out);
}

// Round 9
// 675.275 us; speedup vs baseline: 1.2936x; 1.2936x over previous
//
#include <hip/hip_runtime.h>

// VariationalLSTM: B=65536, T=24, H=64. 4096 WGs x 256 thr (4 waves); each WG owns
// ONE 16-row batch tile. Wave w owns gate units u = 16w + (lane&15) for all gates.
// LDS tiles (R1-proven): bf16 [16 m][64 u], XOR swizzle byte ^= (m&7)<<4;
// A-frags ds_read_b128; A/B share k-map f(kk,hi,e)=32kk+8hi+e. 2 barriers/step
// (R1 race-free schedule). cvt_pk stores.
//
// Occupancy model (R1-R8 verified): builtin MFMA + __launch_bounds__(256,N) =>
// 512/N total regs/thread split ~half arch / half AGPR; runtime waves/SIMD = N.
// N=3: arch cap 84, AGPR 85. Fit:
//  - 21/24 weight frags pinned to AGPR ("+a" empty asm) = 84 AGPR.
//  - biases/x-coeffs (12) + packed masks (8) live in LDS tables, re-read per
//    step via VOLATILE loads (stops the compiler hoisting them back to regs).
//  - R8 spilled ~21 regs (FETCH 2.2GB); these cuts (-28) bring arch to ~75.
// asm MFMA abandoned (R6/R7): opaque to hazard recognizer -> corruption.
//
// Prescale folded into weights: i,f,o rows scaled by -log2e (sig=rcp(1+exp2));
// g rows by +2*log2e (tanh = 1-2*rcp(1+exp2)). Masks {0,1.25} are bf16-exact.

typedef short short8v __attribute__((ext_vector_type(8)));
typedef float f32x4 __attribute__((ext_vector_type(4)));

#define LOG2E 1.44269504088896340736f

__device__ inline float gsig(float y){
  return __builtin_amdgcn_rcpf(1.0f + __builtin_amdgcn_exp2f(y));
}
__device__ inline float gtanh(float y){
  float s = __builtin_amdgcn_rcpf(1.0f + __builtin_amdgcn_exp2f(y));
  return fmaf(-2.0f, s, 1.0f);
}
__device__ inline float ftanh(float x){
  float e = __builtin_amdgcn_exp2f((2.0f * LOG2E) * x);
  return fmaf(-2.0f, __builtin_amdgcn_rcpf(1.0f + e), 1.0f);
}
__device__ inline unsigned short bf16c(float f){
  unsigned uu = __builtin_bit_cast(unsigned, f);
  uu = (uu + 0x7fffu + ((uu >> 16) & 1u)) >> 16;
  return (unsigned short)uu;
}
__device__ inline float unpk(unsigned p, int h){   // exact bf16->f32
  unsigned b = h ? (p & 0xffff0000u) : (p << 16);
  return __builtin_bit_cast(float, b);
}

#define PK_STORE4(T, I, f0, f1, f2, f3) do{                       \
    unsigned _w01, _w23;                                          \
    asm("v_cvt_pk_bf16_f32 %0, %1, %2" : "=v"(_w01) : "v"(f0), "v"(f1)); \
    asm("v_cvt_pk_bf16_f32 %0, %1, %2" : "=v"(_w23) : "v"(f2), "v"(f3)); \
    (T)[(I)[0]] = (unsigned short)_w01;                           \
    (T)[(I)[1]] = (unsigned short)(_w01 >> 16);                   \
    (T)[(I)[2]] = (unsigned short)_w23;                           \
    (T)[(I)[3]] = (unsigned short)(_w23 >> 16);                   \
  }while(0)

__global__ __launch_bounds__(256, 3) void vlstm_kernel(
    const float* __restrict__ x,
    const float* __restrict__ Wih1, const float* __restrict__ Whh1,
    const float* __restrict__ bih1, const float* __restrict__ bhh1,
    const float* __restrict__ Wih2, const float* __restrict__ Whh2,
    const float* __restrict__ bih2, const float* __restrict__ bhh2,
    const float* __restrict__ Wout, const float* __restrict__ bout,
    const float* __restrict__ h10, const float* __restrict__ c10,
    const float* __restrict__ h20, const float* __restrict__ c20,
    const float* __restrict__ mt1v, const float* __restrict__ mt2v,
    const float* __restrict__ ml1v, const float* __restrict__ ml2v,
    float* __restrict__ out)
{
  __shared__ unsigned short sh1L[1024];   // h1*ml1        (layer2 input)
  __shared__ unsigned short sh1T[1024];   // h1*ml1*mt1    (next-step L1 h)
  __shared__ unsigned short sh2T[1024];   // h2*ml2*mt2    (next-step L2 h)
  __shared__ float h2f[1024];             // final h2 (fp32)
  __shared__ float xlds[384];             // x transposed [24][16]
  __shared__ float btab[768];             // [0]=b1pre [256]=wiv_pre [512]=b2pre, idx j*64+u
  __shared__ unsigned mtab[2048];         // 8 arrays[256]: ml1p0,ml1p1,mt1p0,mt1p1,ml2p0,ml2p1,mt2p0,mt2p1

  const int tid = threadIdx.x;
  const int w  = tid >> 6;
  const int l  = tid & 63;
  const int hi = l >> 4;
  const int lo = l & 15;
  const int u  = 16 * w + lo;

  // ---- one-time: weight B-fragments (k-map 32kk+8hi+e), prescaled ----
  short8v fr1[4][2], frI[4][2], frH[4][2];
#pragma unroll
  for (int j = 0; j < 4; ++j){
    const float sc = (j == 2) ? (2.0f * LOG2E) : (-LOG2E);
    int n = u + 64 * j;
#pragma unroll
    for (int kk = 0; kk < 2; ++kk){
      int off = n * 64 + 32 * kk + 8 * hi;
      short8v s;
#pragma unroll
      for (int e = 0; e < 8; ++e) s[e] = (short)bf16c(sc * Whh1[off + e]);
      fr1[j][kk] = s;
#pragma unroll
      for (int e = 0; e < 8; ++e) s[e] = (short)bf16c(sc * Wih2[off + e]);
      frI[j][kk] = s;
#pragma unroll
      for (int e = 0; e < 8; ++e) s[e] = (short)bf16c(sc * Whh2[off + e]);
      frH[j][kk] = s;
    }
  }
  // Pin 21/24 frags into the AGPR half (84 <= 85).
  asm volatile("" :
    "+a"(fr1[0][0]), "+a"(fr1[0][1]), "+a"(fr1[1][0]), "+a"(fr1[1][1]),
    "+a"(fr1[2][0]), "+a"(fr1[2][1]), "+a"(fr1[3][0]), "+a"(fr1[3][1]),
    "+a"(frI[0][0]), "+a"(frI[0][1]), "+a"(frI[1][0]), "+a"(frI[1][1]),
    "+a"(frI[2][0]), "+a"(frI[2][1]), "+a"(frI[3][0]), "+a"(frI[3][1]),
    "+a"(frH[0][0]), "+a"(frH[0][1]), "+a"(frH[1][0]), "+a"(frH[1][1]),
    "+a"(frH[2][0]));

  // ---- bias / x-coeff table (tid enumerates n = j*64+u exactly) ----
  {
    int j = tid >> 6;
    float sc = (j == 2) ? (2.0f * LOG2E) : (-LOG2E);
    btab[tid]       = sc * (bih1[tid] + bhh1[tid]);
    btab[256 + tid] = sc * Wih1[tid];
    btab[512 + tid] = sc * (bih2[tid] + bhh2[tid]);
  }

  // ---- swizzled LDS offsets ----
  int wIdx[4];
#pragma unroll
  for (int r = 0; r < 4; ++r){
    int m = 4 * hi + r;
    wIdx[r] = ((m * 128 + u * 2) ^ ((m & 7) << 4)) >> 1;
  }
  int rIdx[2];
#pragma unroll
  for (int kk = 0; kk < 2; ++kk){
    rIdx[kk] = ((lo * 128 + kk * 64 + hi * 16) ^ ((lo & 7) << 4)) >> 1;
  }

  const int row0 = blockIdx.x * 16;

  for (int idx = tid; idx < 384; idx += 256){
    int r = idx / 24, tt = idx - r * 24;
    xlds[tt * 16 + r] = x[(row0 + r) * 24 + tt];
  }
  float c1r[4], c2r[4];
  {
    float mlt1[4], mtt1[4], mlt2[4], mtt2[4], h1i[4], h2i[4];
#pragma unroll
    for (int r = 0; r < 4; ++r){
      int gofs = (row0 + 4 * hi + r) * 64 + u;
      c1r[r]  = c10[gofs];  c2r[r]  = c20[gofs];
      mlt1[r] = ml1v[gofs]; mlt2[r] = ml2v[gofs];
      mtt1[r] = mt1v[gofs]; mtt2[r] = mt2v[gofs];
      h1i[r] = h10[gofs] * mtt1[r];
      h2i[r] = h20[gofs] * mtt2[r];
    }
    mtab[tid]        = (unsigned)bf16c(mlt1[0]) | ((unsigned)bf16c(mlt1[1]) << 16);
    mtab[256 + tid]  = (unsigned)bf16c(mlt1[2]) | ((unsigned)bf16c(mlt1[3]) << 16);
    mtab[512 + tid]  = (unsigned)bf16c(mtt1[0]) | ((unsigned)bf16c(mtt1[1]) << 16);
    mtab[768 + tid]  = (unsigned)bf16c(mtt1[2]) | ((unsigned)bf16c(mtt1[3]) << 16);
    mtab[1024 + tid] = (unsigned)bf16c(mlt2[0]) | ((unsigned)bf16c(mlt2[1]) << 16);
    mtab[1280 + tid] = (unsigned)bf16c(mlt2[2]) | ((unsigned)bf16c(mlt2[3]) << 16);
    mtab[1536 + tid] = (unsigned)bf16c(mtt2[0]) | ((unsigned)bf16c(mtt2[1]) << 16);
    mtab[1792 + tid] = (unsigned)bf16c(mtt2[2]) | ((unsigned)bf16c(mtt2[3]) << 16);
    PK_STORE4(sh1T, wIdx, h1i[0], h1i[1], h1i[2], h1i[3]);
    PK_STORE4(sh2T, wIdx, h2i[0], h2i[1], h2i[2], h2i[3]);
  }
  __syncthreads();

  short8v a1[2], at2[2];
  a1[0]  = *(const short8v*)&sh1T[rIdx[0]];
  a1[1]  = *(const short8v*)&sh1T[rIdx[1]];
  at2[0] = *(const short8v*)&sh2T[rIdx[0]];
  at2[1] = *(const short8v*)&sh2T[rIdx[1]];

#pragma unroll 1
  for (int t = 0; t < 24; ++t){
    f32x4 xv = *(const f32x4*)&xlds[t * 16 + 4 * hi];

    // ---- layer 1 (a1 preloaded; at2 held for L2) ----
    f32x4 gt[4];
#pragma unroll
    for (int j = 0; j < 4; ++j){
      float wv = *(volatile const float*)&btab[256 + j * 64 + u];
      float bb = *(volatile const float*)&btab[j * 64 + u];
      f32x4 acc;
#pragma unroll
      for (int r = 0; r < 4; ++r) acc[r] = fmaf(xv[r], wv, bb);
      acc = __builtin_amdgcn_mfma_f32_16x16x32_bf16(a1[0], fr1[j][0], acc, 0, 0, 0);
      acc = __builtin_amdgcn_mfma_f32_16x16x32_bf16(a1[1], fr1[j][1], acc, 0, 0, 0);
      gt[j] = acc;
    }
    {
      unsigned mL0 = *(volatile const unsigned*)&mtab[tid];
      unsigned mL1_= *(volatile const unsigned*)&mtab[256 + tid];
      unsigned mT0 = *(volatile const unsigned*)&mtab[512 + tid];
      unsigned mT1 = *(volatile const unsigned*)&mtab[768 + tid];
      float h1l[4], h1t[4];
#pragma unroll
      for (int r = 0; r < 4; ++r){
        float ti = gsig(gt[0][r]);
        float tf = gsig(gt[1][r]);
        float tg = gtanh(gt[2][r]);
        float to = gsig(gt[3][r]);
        float cn = fmaf(tf, c1r[r], ti * tg);
        c1r[r] = cn;
        h1l[r] = to * ftanh(cn) * unpk(r < 2 ? mL0 : mL1_, r & 1);
        h1t[r] = h1l[r] * unpk(r < 2 ? mT0 : mT1, r & 1);
      }
      PK_STORE4(sh1L, wIdx, h1l[0], h1l[1], h1l[2], h1l[3]);
      PK_STORE4(sh1T, wIdx, h1t[0], h1t[1], h1t[2], h1t[3]);
    }

    __syncthreads();   // barrier 1

    short8v a2[2];
    a2[0] = *(const short8v*)&sh1L[rIdx[0]];
    a2[1] = *(const short8v*)&sh1L[rIdx[1]];
    a1[0] = *(const short8v*)&sh1T[rIdx[0]];   // next step's L1 input (window b1..b2)
    a1[1] = *(const short8v*)&sh1T[rIdx[1]];

    // ---- layer 2 (at2 from previous loop-end read) ----
#pragma unroll
    for (int j = 0; j < 4; ++j){
      float bb = *(volatile const float*)&btab[512 + j * 64 + u];
      f32x4 acc;
#pragma unroll
      for (int r = 0; r < 4; ++r) acc[r] = bb;
      acc = __builtin_amdgcn_mfma_f32_16x16x32_bf16(a2[0],  frI[j][0], acc, 0, 0, 0);
      acc = __builtin_amdgcn_mfma_f32_16x16x32_bf16(a2[1],  frI[j][1], acc, 0, 0, 0);
      acc = __builtin_amdgcn_mfma_f32_16x16x32_bf16(at2[0], frH[j][0], acc, 0, 0, 0);
      acc = __builtin_amdgcn_mfma_f32_16x16x32_bf16(at2[1], frH[j][1], acc, 0, 0, 0);
      gt[j] = acc;
    }
    {
      unsigned mL0 = *(volatile const unsigned*)&mtab[1024 + tid];
      unsigned mL1_= *(volatile const unsigned*)&mtab[1280 + tid];
      unsigned mT0 = *(volatile const unsigned*)&mtab[1536 + tid];
      unsigned mT1 = *(volatile const unsigned*)&mtab[1792 + tid];
      float h2t[4];
#pragma unroll
      for (int r = 0; r < 4; ++r){
        float ti = gsig(gt[0][r]);
        float tf = gsig(gt[1][r]);
        float tg = gtanh(gt[2][r]);
        float to = gsig(gt[3][r]);
        float cn = fmaf(tf, c2r[r], ti * tg);
        c2r[r] = cn;
        float h2l = to * ftanh(cn) * unpk(r < 2 ? mL0 : mL1_, r & 1);
        h2t[r] = h2l * unpk(r < 2 ? mT0 : mT1, r & 1);
        if (t == 23) h2f[(4 * hi + r) * 64 + u] = h2l;
      }
      PK_STORE4(sh2T, wIdx, h2t[0], h2t[1], h2t[2], h2t[3]);
    }

    __syncthreads();   // barrier 2

    at2[0] = *(const short8v*)&sh2T[rIdx[0]];  // next step's L2 h (window b2..b1')
    at2[1] = *(const short8v*)&sh2T[rIdx[1]];
  }

  // ---- output: out[row][o] = sum_u h2f[row][u]*Wout[o][u] + bout[o] ----
  if (tid < 32){
    int r = tid & 15, o = tid >> 4;
    float acc = bout[o];
#pragma unroll 8
    for (int uu = 0; uu < 64; ++uu)
      acc = fmaf(h2f[r * 64 + uu], Wout[o * 64 + uu], acc);
    out[(row0 + r) * 2 + o] = acc;
  }
}

extern "C" void kernel_launch(void* const* d_in, const int* in_sizes, int n_in,
                              void* d_out, int out_size, void* d_ws, size_t ws_size,
                              hipStream_t stream)
{
  vlstm_kernel<<<dim3(4096), dim3(256), 0, stream>>>(
      (const float*)d_in[0],  (const float*)d_in[1],  (const float*)d_in[2],
      (const float*)d_in[3],  (const float*)d_in[4],  (const float*)d_in[5],
      (const float*)d_in[6],  (const float*)d_in[7],  (const float*)d_in[8],
      (const float*)d_in[9],  (const float*)d_in[10], (const float*)d_in[11],
      (const float*)d_in[12], (const float*)d_in[13], (const float*)d_in[14],
      (const float*)d_in[15], (const float*)d_in[16], (const float*)d_in[17],
      (const float*)d_in[18], (float*)d_out);
}